// Round 9
// baseline (102.633 us; speedup 1.0000x reference)
//
#include <hip/hip_runtime.h>
#include <hip/hip_fp16.h>

// Problem constants (fixed by the reference)
constexpr int Bsz  = 512;
constexpr int Nn   = 256;   // agents
constexpr int FINc = 32;
constexpr int H1c  = 16;
constexpr int Gc   = 8;
constexpr int FOUTc= 16;
constexpr int Kc   = 3;
constexpr int ACTc = 5;

// Counted waitcnt (T4 discipline): literal immediates, memory clobber pins
// all memory ops; DS ops complete in-order so lgkmcnt(3) == "reads older
// than the previous iteration are done".
#define VMCNT0()  asm volatile("s_waitcnt vmcnt(0)" ::: "memory")
#define VMCNT1()  asm volatile("s_waitcnt vmcnt(1)" ::: "memory")
#define LGKMCNT3() asm volatile("s_waitcnt lgkmcnt(3)" ::: "memory")

// Async global->LDS DMA: 64 lanes x 16 B = one full 1 KB S-row per issue.
// Global src is per-lane (4*lane floats); LDS dst is wave-uniform base,
// HW writes base + lane*16 (linear) -- matches sS[w][slot][4*lane..+3].
// NOTE: body gated on __HIP_DEVICE_COMPILE__ — the builtin does not exist in
// the host pass (round-8 compile failure was the host pass hitting #error).
__device__ __forceinline__ void stage_row(const float* g, float* lds) {
#if defined(__HIP_DEVICE_COMPILE__)
    __builtin_amdgcn_global_load_lds(
        (const __attribute__((address_space(1))) void*)g,
        (__attribute__((address_space(3))) void*)lds, 16, 0, 0);
#else
    (void)g; (void)lds;
#endif
}

// One block per batch. 512 threads = 8 waves, 2 blocks/CU (64 KB LDS each).
// Wave w owns S rows [32w, 32w+32) x all 256 cols; lane owns cols 4l..4l+3.
// S rows staged via global_load_lds into a 4-slot/1KB ring per wave,
// depth-2 DMA pipeline, counted vmcnt (never 0 until tail), no VGPR cost.
__global__ __launch_bounds__(512, 4)
void cpn_kernel(const float* __restrict__ x,  const float* __restrict__ S,
                const float* __restrict__ W1, const float* __restrict__ b1,
                const float* __restrict__ W2, const float* __restrict__ b2,
                const float* __restrict__ Hgf,const float* __restrict__ bgf,
                const float* __restrict__ Wa, const float* __restrict__ ba,
                float* __restrict__ out)
{
    const int b    = blockIdx.x;
    const int tid  = threadIdx.x;
    const int wid  = tid >> 6;
    const int lane = tid & 63;
    const int n    = tid;            // agent for phases A/C (tid < 256 only)

    __shared__ __align__(16) float  sS[8][4][Nn];      // staging ring, 32 KB
    __shared__ __align__(16) float  zA[Nn][Gc];        // z0 f32, 8 KB
    __shared__ __align__(16) float  zB[Nn][Gc];        // z1 f32, 8 KB
    __shared__ __align__(16) __half zpart[4][Gc][Nn];  // f16 partials, 16 KB  (total 64 KB)

    // ---------------- Phase A: compress MLP (thread = agent n, tid<256) ----------------
    if (tid < Nn) {
        float xr[FINc];
        const float4* xp = reinterpret_cast<const float4*>(x + ((size_t)b * Nn + n) * FINc);
        #pragma unroll
        for (int i = 0; i < FINc / 4; ++i) {
            float4 v = xp[i];
            xr[4*i+0] = v.x; xr[4*i+1] = v.y; xr[4*i+2] = v.z; xr[4*i+3] = v.w;
        }
        float h1v[H1c];
        #pragma unroll
        for (int h = 0; h < H1c; ++h) {
            float a = b1[h];
            #pragma unroll
            for (int f = 0; f < FINc; ++f) a = fmaf(W1[h*FINc + f], xr[f], a);
            h1v[h] = fmaxf(a, 0.0f);
        }
        #pragma unroll
        for (int g = 0; g < Gc; ++g) {
            float a = b2[g];
            #pragma unroll
            for (int h = 0; h < H1c; ++h) a = fmaf(W2[g*H1c + h], h1v[h], a);
            zA[n][g] = fmaxf(a, 0.0f);
        }
    }
    __syncthreads();

    // ---------------- S passes: z_k = z_{k-1} @ S ----------------
    auto spass = [&](const float (*zsrc)[Gc]) {
        float acc[Gc][4];
        #pragma unroll
        for (int g = 0; g < Gc; ++g)
            #pragma unroll
            for (int j = 0; j < 4; ++j) acc[g][j] = 0.0f;

        const float* srow0 = S + ((size_t)b * Nn + wid * 32) * Nn + 4 * lane;

        // prologue: rows 0,1 in flight
        stage_row(srow0 + (size_t)0 * Nn, &sS[wid][0][0]);
        stage_row(srow0 + (size_t)1 * Nn, &sS[wid][1][0]);

        #pragma unroll
        for (int i = 0; i < 32; ++i) {
            if (i == 31) { VMCNT0(); } else { VMCNT1(); }   // row i landed in LDS
            LGKMCNT3();                                      // slot (i+2)&3's old reads done
            if (i < 30)
                stage_row(srow0 + (size_t)(i + 2) * Nn, &sS[wid][(i + 2) & 3][0]);

            const float4 sv = *reinterpret_cast<const float4*>(&sS[wid][i & 3][4 * lane]);
            const int nn = wid * 32 + i;
            const float4 za = *reinterpret_cast<const float4*>(&zsrc[nn][0]); // b128 broadcast
            const float4 zb = *reinterpret_cast<const float4*>(&zsrc[nn][4]);
            const float zg[Gc] = {za.x, za.y, za.z, za.w, zb.x, zb.y, zb.z, zb.w};
            #pragma unroll
            for (int g = 0; g < Gc; ++g) {
                acc[g][0] = fmaf(zg[g], sv.x, acc[g][0]);
                acc[g][1] = fmaf(zg[g], sv.y, acc[g][1]);
                acc[g][2] = fmaf(zg[g], sv.z, acc[g][2]);
                acc[g][3] = fmaf(zg[g], sv.w, acc[g][3]);
            }
        }

        // Two-phase merge into f16 partials: waves 0-3 store, waves 4-7 RMW.
        if (wid < 4) {
            #pragma unroll
            for (int g = 0; g < Gc; ++g) {
                *reinterpret_cast<__half2*>(&zpart[wid][g][4*lane+0]) =
                    __floats2half2_rn(acc[g][0], acc[g][1]);
                *reinterpret_cast<__half2*>(&zpart[wid][g][4*lane+2]) =
                    __floats2half2_rn(acc[g][2], acc[g][3]);
            }
        }
        __syncthreads();
        if (wid >= 4) {
            #pragma unroll
            for (int g = 0; g < Gc; ++g) {
                __half2 c01 = *reinterpret_cast<__half2*>(&zpart[wid-4][g][4*lane+0]);
                __half2 c23 = *reinterpret_cast<__half2*>(&zpart[wid-4][g][4*lane+2]);
                *reinterpret_cast<__half2*>(&zpart[wid-4][g][4*lane+0]) =
                    __floats2half2_rn(__low2float(c01) + acc[g][0],
                                      __high2float(c01) + acc[g][1]);
                *reinterpret_cast<__half2*>(&zpart[wid-4][g][4*lane+2]) =
                    __floats2half2_rn(__low2float(c23) + acc[g][2],
                                      __high2float(c23) + acc[g][3]);
            }
        }
        __syncthreads();
    };

    auto merge = [&](float* zr) {      // sum 4 merged partials (tid<256)
        #pragma unroll
        for (int g = 0; g < Gc; ++g) {
            float a = 0.0f;
            #pragma unroll
            for (int r = 0; r < 4; ++r) a += __half2float(zpart[r][g][n]);
            zr[g] = a;
        }
    };

    spass(zA);
    if (tid < Nn) {
        float z1r[Gc];
        merge(z1r);
        #pragma unroll
        for (int g = 0; g < Gc; ++g) zB[n][g] = z1r[g];    // publish z1
    }
    __syncthreads();                                        // guards zB + ring reuse
    spass(zB);

    // ---------------- Phase C: graph filter + action head (tid<256) ----------------
    if (tid < Nn) {
        float z2r[Gc];
        merge(z2r);

        const float4 a0 = *reinterpret_cast<const float4*>(&zA[n][0]);
        const float4 a1 = *reinterpret_cast<const float4*>(&zA[n][4]);
        const float4 c0 = *reinterpret_cast<const float4*>(&zB[n][0]);
        const float4 c1 = *reinterpret_cast<const float4*>(&zB[n][4]);
        const float z0g[Gc] = {a0.x, a0.y, a0.z, a0.w, a1.x, a1.y, a1.z, a1.w};
        const float z1g[Gc] = {c0.x, c0.y, c0.z, c0.w, c1.x, c1.y, c1.z, c1.w};

        float y[FOUTc];
        #pragma unroll
        for (int f = 0; f < FOUTc; ++f) y[f] = bgf[f];
        #pragma unroll
        for (int g = 0; g < Gc; ++g) {
            #pragma unroll
            for (int f = 0; f < FOUTc; ++f) y[f] = fmaf(Hgf[f*(Kc*Gc) + 0*Gc + g], z0g[g], y[f]);
        }
        #pragma unroll
        for (int g = 0; g < Gc; ++g) {
            #pragma unroll
            for (int f = 0; f < FOUTc; ++f) y[f] = fmaf(Hgf[f*(Kc*Gc) + 1*Gc + g], z1g[g], y[f]);
        }
        #pragma unroll
        for (int g = 0; g < Gc; ++g) {
            #pragma unroll
            for (int f = 0; f < FOUTc; ++f) y[f] = fmaf(Hgf[f*(Kc*Gc) + 2*Gc + g], z2r[g], y[f]);
        }
        #pragma unroll
        for (int f = 0; f < FOUTc; ++f) y[f] = fmaxf(y[f], 0.0f);

        float* op = out + ((size_t)b * Nn + n) * ACTc;
        #pragma unroll
        for (int a = 0; a < ACTc; ++a) {
            float acc = ba[a];
            #pragma unroll
            for (int f = 0; f < FOUTc; ++f) acc = fmaf(Wa[a*FOUTc + f], y[f], acc);
            op[a] = acc;
        }
    }
}

extern "C" void kernel_launch(void* const* d_in, const int* in_sizes, int n_in,
                              void* d_out, int out_size, void* d_ws, size_t ws_size,
                              hipStream_t stream) {
    const float* x   = (const float*)d_in[0];
    const float* S   = (const float*)d_in[1];
    const float* W1  = (const float*)d_in[2];
    const float* b1  = (const float*)d_in[3];
    const float* W2  = (const float*)d_in[4];
    const float* b2  = (const float*)d_in[5];
    const float* Hgf = (const float*)d_in[6];
    const float* bgf = (const float*)d_in[7];
    const float* Wa  = (const float*)d_in[8];
    const float* ba  = (const float*)d_in[9];

    cpn_kernel<<<dim3(Bsz), dim3(512), 0, stream>>>(
        x, S, W1, b1, W2, b2, Hgf, bgf, Wa, ba, (float*)d_out);
}

// Round 10
// 67.550 us; speedup vs baseline: 1.5194x; 1.5194x over previous
//
#include <hip/hip_runtime.h>
#include <hip/hip_fp16.h>

// Problem constants (fixed by the reference)
constexpr int Bsz  = 512;
constexpr int Nn   = 256;   // agents
constexpr int FINc = 32;
constexpr int H1c  = 16;
constexpr int Gc   = 8;
constexpr int FOUTc= 16;
constexpr int Kc   = 3;
constexpr int ACTc = 5;

// One block per batch, one block per CU (156 KB LDS). 1024 threads = 16 waves
// = 8 row-groups x 2 col-groups. Pass 1 reads S f32 from global (L3), FMAs at
// full precision, and stages an f16 copy of S into LDS; pass 2 runs entirely
// from LDS. Each wave stages exactly the S fragment it re-reads -> no
// cross-wave staging dependency. L3 traffic: 268 MB -> ~153 MB per call.
__global__ __launch_bounds__(1024, 4)
void cpn_kernel(const float* __restrict__ x,  const float* __restrict__ S,
                const float* __restrict__ W1, const float* __restrict__ b1,
                const float* __restrict__ W2, const float* __restrict__ b2,
                const float* __restrict__ Hgf,const float* __restrict__ bgf,
                const float* __restrict__ Wa, const float* __restrict__ ba,
                float* __restrict__ out)
{
    const int b    = blockIdx.x;
    const int tid  = threadIdx.x;
    const int wid  = tid >> 6;       // 0..15
    const int lane = tid & 63;
    const int rg   = wid >> 1;       // 0..7  rows [32rg, 32rg+32)
    const int cg   = wid & 1;        // 0..1  cols [128cg, 128cg+128)
    const int n    = tid;            // agent for phases A/C (tid < 256 only)

    __shared__ __align__(16) __half S16[Nn][Nn];       // f16 copy of S (128 KB)
    __shared__ __align__(16) float  zA[Nn][Gc];        // z0 f32 (8 KB)
    __shared__ __align__(16) __half zBh[Nn][Gc];       // z1 f16 (4 KB)
    __shared__ __align__(16) __half zpart[4][Gc][Nn];  // f16 partials (16 KB) => 156 KB total

    // ---------------- Phase A: compress MLP (thread = agent n, tid<256) ----------------
    if (tid < Nn) {
        float xr[FINc];
        const float4* xp = reinterpret_cast<const float4*>(x + ((size_t)b * Nn + n) * FINc);
        #pragma unroll
        for (int i = 0; i < FINc / 4; ++i) {
            float4 v = xp[i];
            xr[4*i+0] = v.x; xr[4*i+1] = v.y; xr[4*i+2] = v.z; xr[4*i+3] = v.w;
        }
        float h1v[H1c];
        #pragma unroll
        for (int h = 0; h < H1c; ++h) {
            float a = b1[h];
            #pragma unroll
            for (int f = 0; f < FINc; ++f) a = fmaf(W1[h*FINc + f], xr[f], a);
            h1v[h] = fmaxf(a, 0.0f);
        }
        #pragma unroll
        for (int g = 0; g < Gc; ++g) {
            float a = b2[g];
            #pragma unroll
            for (int h = 0; h < H1c; ++h) a = fmaf(W2[g*H1c + h], h1v[h], a);
            zA[n][g] = fmaxf(a, 0.0f);
        }
    }
    __syncthreads();

    // Two-phase f16 partial merge shared by both passes (R9-proven structure).
    auto merge_store = [&](const float (&acc)[Gc][2]) {
        if (rg < 4) {
            #pragma unroll
            for (int g = 0; g < Gc; ++g)
                *reinterpret_cast<__half2*>(&zpart[rg][g][cg*128 + 2*lane]) =
                    __floats2half2_rn(acc[g][0], acc[g][1]);
        }
        __syncthreads();
        if (rg >= 4) {
            #pragma unroll
            for (int g = 0; g < Gc; ++g) {
                __half2 c = *reinterpret_cast<__half2*>(&zpart[rg-4][g][cg*128 + 2*lane]);
                *reinterpret_cast<__half2*>(&zpart[rg-4][g][cg*128 + 2*lane]) =
                    __floats2half2_rn(__low2float(c) + acc[g][0],
                                      __high2float(c) + acc[g][1]);
            }
        }
        __syncthreads();
    };

    // ---------------- Pass 1: z1 = z0 @ S  (S from global f32, stage f16 to LDS) --------
    {
        float acc[Gc][2];
        #pragma unroll
        for (int g = 0; g < Gc; ++g) { acc[g][0] = 0.0f; acc[g][1] = 0.0f; }

        const float* srow = S + ((size_t)b * Nn + rg * 32) * Nn + cg * 128 + 2 * lane;
        #pragma unroll 8
        for (int i = 0; i < 32; ++i) {
            const float2 sv = *reinterpret_cast<const float2*>(srow);  // coalesced 8B/lane
            srow += Nn;
            const int nn = rg * 32 + i;
            const float4 za = *reinterpret_cast<const float4*>(&zA[nn][0]); // b128 broadcast
            const float4 zb = *reinterpret_cast<const float4*>(&zA[nn][4]);
            const float zg[Gc] = {za.x, za.y, za.z, za.w, zb.x, zb.y, zb.z, zb.w};
            #pragma unroll
            for (int g = 0; g < Gc; ++g) {
                acc[g][0] = fmaf(zg[g], sv.x, acc[g][0]);
                acc[g][1] = fmaf(zg[g], sv.y, acc[g][1]);
            }
            // stage this fragment of S as f16 (2-way bank aliasing = free)
            *reinterpret_cast<__half2*>(&S16[nn][cg*128 + 2*lane]) = __float22half2_rn(sv);
        }
        merge_store(acc);
    }
    // merge partials -> publish z1 as f16 (tid<256)
    if (tid < Nn) {
        __half2 ph[4];
        #pragma unroll
        for (int g2 = 0; g2 < 4; ++g2) {
            float a0 = 0.0f, a1 = 0.0f;
            #pragma unroll
            for (int r = 0; r < 4; ++r) {
                a0 += __half2float(zpart[r][2*g2+0][n]);
                a1 += __half2float(zpart[r][2*g2+1][n]);
            }
            ph[g2] = __floats2half2_rn(a0, a1);
        }
        *reinterpret_cast<float4*>(&zBh[n][0]) = *reinterpret_cast<const float4*>(ph);
    }
    __syncthreads();

    // ---------------- Pass 2: z2 = z1 @ S  (entirely from LDS) ----------------
    float z2r[Gc];
    {
        float acc[Gc][2];
        #pragma unroll
        for (int g = 0; g < Gc; ++g) { acc[g][0] = 0.0f; acc[g][1] = 0.0f; }

        #pragma unroll 8
        for (int i = 0; i < 32; ++i) {
            const int nn = rg * 32 + i;
            const __half2 sh = *reinterpret_cast<const __half2*>(&S16[nn][cg*128 + 2*lane]);
            const float2 sv = __half22float2(sh);
            float4 raw = *reinterpret_cast<const float4*>(&zBh[nn][0]);  // b128 broadcast
            const __half2* hp = reinterpret_cast<const __half2*>(&raw);
            const float2 z01 = __half22float2(hp[0]);
            const float2 z23 = __half22float2(hp[1]);
            const float2 z45 = __half22float2(hp[2]);
            const float2 z67 = __half22float2(hp[3]);
            const float zg[Gc] = {z01.x, z01.y, z23.x, z23.y, z45.x, z45.y, z67.x, z67.y};
            #pragma unroll
            for (int g = 0; g < Gc; ++g) {
                acc[g][0] = fmaf(zg[g], sv.x, acc[g][0]);
                acc[g][1] = fmaf(zg[g], sv.y, acc[g][1]);
            }
        }
        merge_store(acc);
    }
    if (tid < Nn) {
        #pragma unroll
        for (int g = 0; g < Gc; ++g) {
            float a = 0.0f;
            #pragma unroll
            for (int r = 0; r < 4; ++r) a += __half2float(zpart[r][g][n]);
            z2r[g] = a;
        }
    }

    // ---------------- Phase C: graph filter + action head (tid<256) ----------------
    if (tid < Nn) {
        const float4 a0 = *reinterpret_cast<const float4*>(&zA[n][0]);
        const float4 a1 = *reinterpret_cast<const float4*>(&zA[n][4]);
        float4 rawB = *reinterpret_cast<const float4*>(&zBh[n][0]);
        const __half2* hb = reinterpret_cast<const __half2*>(&rawB);
        const float2 f01 = __half22float2(hb[0]);
        const float2 f23 = __half22float2(hb[1]);
        const float2 f45 = __half22float2(hb[2]);
        const float2 f67 = __half22float2(hb[3]);
        const float z0g[Gc] = {a0.x, a0.y, a0.z, a0.w, a1.x, a1.y, a1.z, a1.w};
        const float z1g[Gc] = {f01.x, f01.y, f23.x, f23.y, f45.x, f45.y, f67.x, f67.y};

        float y[FOUTc];
        #pragma unroll
        for (int f = 0; f < FOUTc; ++f) y[f] = bgf[f];
        #pragma unroll
        for (int g = 0; g < Gc; ++g) {
            #pragma unroll
            for (int f = 0; f < FOUTc; ++f) y[f] = fmaf(Hgf[f*(Kc*Gc) + 0*Gc + g], z0g[g], y[f]);
        }
        #pragma unroll
        for (int g = 0; g < Gc; ++g) {
            #pragma unroll
            for (int f = 0; f < FOUTc; ++f) y[f] = fmaf(Hgf[f*(Kc*Gc) + 1*Gc + g], z1g[g], y[f]);
        }
        #pragma unroll
        for (int g = 0; g < Gc; ++g) {
            #pragma unroll
            for (int f = 0; f < FOUTc; ++f) y[f] = fmaf(Hgf[f*(Kc*Gc) + 2*Gc + g], z2r[g], y[f]);
        }
        #pragma unroll
        for (int f = 0; f < FOUTc; ++f) y[f] = fmaxf(y[f], 0.0f);

        float* op = out + ((size_t)b * Nn + n) * ACTc;
        #pragma unroll
        for (int a = 0; a < ACTc; ++a) {
            float acc = ba[a];
            #pragma unroll
            for (int f = 0; f < FOUTc; ++f) acc = fmaf(Wa[a*FOUTc + f], y[f], acc);
            op[a] = acc;
        }
    }
}

extern "C" void kernel_launch(void* const* d_in, const int* in_sizes, int n_in,
                              void* d_out, int out_size, void* d_ws, size_t ws_size,
                              hipStream_t stream) {
    const float* x   = (const float*)d_in[0];
    const float* S   = (const float*)d_in[1];
    const float* W1  = (const float*)d_in[2];
    const float* b1  = (const float*)d_in[3];
    const float* W2  = (const float*)d_in[4];
    const float* b2  = (const float*)d_in[5];
    const float* Hgf = (const float*)d_in[6];
    const float* bgf = (const float*)d_in[7];
    const float* Wa  = (const float*)d_in[8];
    const float* ba  = (const float*)d_in[9];

    cpn_kernel<<<dim3(Bsz), dim3(1024), 0, stream>>>(
        x, S, W1, b1, W2, b2, Hgf, bgf, Wa, ba, (float*)d_out);
}